// Round 1
// baseline (891.196 us; speedup 1.0000x reference)
//
#include <hip/hip_runtime.h>

#define NN 20000
#define EE 320000
#define TE 340000   // EE + NN self loops
#define NEG 0.2f

__device__ __forceinline__ unsigned fenc(float x) {
    unsigned b = __float_as_uint(x);
    return (b & 0x80000000u) ? ~b : (b | 0x80000000u);
}
__device__ __forceinline__ float fdec(unsigned u) {
    unsigned b = (u & 0x80000000u) ? (u ^ 0x80000000u) : ~u;
    return __uint_as_float(b);
}

// ---------------- init: out = bias broadcast, zero stats ----------------
__global__ __launch_bounds__(256) void k_init(const float* __restrict__ b, float* __restrict__ out,
                                              unsigned* __restrict__ hmax, float* __restrict__ hsum) {
    int gid = blockIdx.x * 256 + threadIdx.x;
    int stride = gridDim.x * 256;
    for (int i = gid; i < NN * 256; i += stride) out[i] = b[i & 255];
    if (gid < 4) { hmax[gid] = 0u; hsum[gid] = 0.0f; }
}

// ---------------- fp32 GEMM: h = x @ W  (20000x256 @ 256x256) ----------------
// tile 64 rows x 128 cols, 256 threads (16x16), each thread 4x8 outputs
__global__ __launch_bounds__(256) void k_gemm(const float* __restrict__ x, const float* __restrict__ W,
                                              float* __restrict__ h) {
    __shared__ float4 xt[64][64];   // [row][k4] : 64 rows x 256 k, 64 KB
    const int tid = threadIdx.x;
    const int rowBlk = blockIdx.x >> 1, colBlk = blockIdx.x & 1;
    const int r0 = rowBlk * 64;
    const int c0 = colBlk * 128;
    const float4* x4 = (const float4*)x;

    #pragma unroll
    for (int i = 0; i < 16; ++i) {
        int slot = tid + i * 256;          // 4096 float4 slots
        int row = slot >> 6, c4 = slot & 63;
        int g = r0 + row;
        float4 v = {0.f, 0.f, 0.f, 0.f};
        if (g < NN) v = x4[g * 64 + c4];
        xt[row][c4] = v;
    }
    __syncthreads();

    const int tx = tid & 15, ty = tid >> 4;
    float acc[4][8];
    #pragma unroll
    for (int r = 0; r < 4; ++r)
        #pragma unroll
        for (int c = 0; c < 8; ++c) acc[r][c] = 0.f;

    const float4* W4 = (const float4*)W;
    const int wcol4 = (c0 >> 2) + tx * 2;   // float4 column index

    for (int k4 = 0; k4 < 64; ++k4) {
        float wv[4][8];
        #pragma unroll
        for (int j = 0; j < 4; ++j) {
            float4 a = W4[(4 * k4 + j) * 64 + wcol4];
            float4 bb = W4[(4 * k4 + j) * 64 + wcol4 + 1];
            wv[j][0] = a.x; wv[j][1] = a.y; wv[j][2] = a.z; wv[j][3] = a.w;
            wv[j][4] = bb.x; wv[j][5] = bb.y; wv[j][6] = bb.z; wv[j][7] = bb.w;
        }
        #pragma unroll
        for (int r = 0; r < 4; ++r) {
            float4 xv = xt[ty * 4 + r][k4];
            float xs[4] = {xv.x, xv.y, xv.z, xv.w};
            #pragma unroll
            for (int c = 0; c < 8; ++c) {
                float s = acc[r][c];
                #pragma unroll
                for (int j = 0; j < 4; ++j) s += xs[j] * wv[j][c];
                acc[r][c] = s;
            }
        }
    }

    float4* h4 = (float4*)h;
    #pragma unroll
    for (int r = 0; r < 4; ++r) {
        int g = r0 + ty * 4 + r;
        if (g < NN) {
            float4 va = {acc[r][0], acc[r][1], acc[r][2], acc[r][3]};
            float4 vb = {acc[r][4], acc[r][5], acc[r][6], acc[r][7]};
            h4[g * 64 + wcol4] = va;
            h4[g * 64 + wcol4 + 1] = vb;
        }
    }
}

// ---------------- per-node attention logits ----------------
// alpha_src[n,h] = sum_d leaky(h[n,h,d]) * att[0,h,d];  alpha_dst with att[0,h,64+d]
__global__ __launch_bounds__(256) void k_alpha(const float* __restrict__ h, const float* __restrict__ att,
                                               float* __restrict__ asrc, float* __restrict__ adst) {
    int node = blockIdx.x;
    int head = threadIdx.x >> 6;
    int lane = threadIdx.x & 63;
    float v = h[node * 256 + head * 64 + lane];
    float lv = v > 0.f ? v : NEG * v;
    float ss = lv * att[head * 128 + lane];
    float sd = lv * att[head * 128 + 64 + lane];
    #pragma unroll
    for (int m = 32; m > 0; m >>= 1) {
        ss += __shfl_xor(ss, m, 64);
        sd += __shfl_xor(sd, m, 64);
    }
    if (lane == 0) { asrc[node * 4 + head] = ss; adst[node * 4 + head] = sd; }
}

// ---------------- edge scores + global per-head max ----------------
__global__ __launch_bounds__(256) void k_score(const int* __restrict__ es, const int* __restrict__ ed,
                                               const float* __restrict__ asrc, const float* __restrict__ adst,
                                               float* __restrict__ sc, unsigned* __restrict__ hmax) {
    int e = blockIdx.x * 256 + threadIdx.x;
    float4 s = {-1e30f, -1e30f, -1e30f, -1e30f};
    if (e < TE) {
        int si = e < EE ? es[e] : e - EE;
        int di = e < EE ? ed[e] : e - EE;
        float4 a = *(const float4*)(asrc + si * 4);
        float4 b = *(const float4*)(adst + di * 4);
        s.x = a.x + b.x; s.y = a.y + b.y; s.z = a.z + b.z; s.w = a.w + b.w;
        *(float4*)(sc + e * 4) = s;
    }
    float m0 = s.x, m1 = s.y, m2 = s.z, m3 = s.w;
    #pragma unroll
    for (int m = 32; m > 0; m >>= 1) {
        m0 = fmaxf(m0, __shfl_xor(m0, m, 64));
        m1 = fmaxf(m1, __shfl_xor(m1, m, 64));
        m2 = fmaxf(m2, __shfl_xor(m2, m, 64));
        m3 = fmaxf(m3, __shfl_xor(m3, m, 64));
    }
    if ((threadIdx.x & 63) == 0) {
        atomicMax(hmax + 0, fenc(m0));
        atomicMax(hmax + 1, fenc(m1));
        atomicMax(hmax + 2, fenc(m2));
        atomicMax(hmax + 3, fenc(m3));
    }
}

// ---------------- p = exp(s - max), global per-head sum ----------------
__global__ __launch_bounds__(256) void k_exp(float* __restrict__ sc, const unsigned* __restrict__ hmax,
                                             float* __restrict__ hsum) {
    int e = blockIdx.x * 256 + threadIdx.x;
    float mx0 = fdec(hmax[0]), mx1 = fdec(hmax[1]), mx2 = fdec(hmax[2]), mx3 = fdec(hmax[3]);
    float p0 = 0.f, p1 = 0.f, p2 = 0.f, p3 = 0.f;
    if (e < TE) {
        float4 s = *(const float4*)(sc + e * 4);
        p0 = __expf(s.x - mx0); p1 = __expf(s.y - mx1);
        p2 = __expf(s.z - mx2); p3 = __expf(s.w - mx3);
        // use precise expf for accuracy instead:
        p0 = expf(s.x - mx0); p1 = expf(s.y - mx1);
        p2 = expf(s.z - mx2); p3 = expf(s.w - mx3);
        float4 p = {p0, p1, p2, p3};
        *(float4*)(sc + e * 4) = p;
    }
    #pragma unroll
    for (int m = 32; m > 0; m >>= 1) {
        p0 += __shfl_xor(p0, m, 64);
        p1 += __shfl_xor(p1, m, 64);
        p2 += __shfl_xor(p2, m, 64);
        p3 += __shfl_xor(p3, m, 64);
    }
    if ((threadIdx.x & 63) == 0) {
        atomicAdd(hsum + 0, p0);
        atomicAdd(hsum + 1, p1);
        atomicAdd(hsum + 2, p2);
        atomicAdd(hsum + 3, p3);
    }
}

// ---------------- scatter: out[dst] += (p/Z) * h[src] ----------------
// one wave per edge; 4 contiguous 256B gathers + 4 contiguous 256B atomic bursts
__global__ __launch_bounds__(256) void k_scatter(const int* __restrict__ es, const int* __restrict__ ed,
                                                 const float* __restrict__ sc, const float* __restrict__ hsum,
                                                 const float* __restrict__ h, float* __restrict__ out) {
    int wid = blockIdx.x * 4 + (threadIdx.x >> 6);
    int lane = threadIdx.x & 63;
    int nw = gridDim.x * 4;
    float4 Z = *(const float4*)hsum;
    float inv[4] = {1.f / Z.x, 1.f / Z.y, 1.f / Z.z, 1.f / Z.w};
    for (int e = wid; e < TE; e += nw) {
        int si = e < EE ? es[e] : e - EE;
        int di = e < EE ? ed[e] : e - EE;
        float4 p = *(const float4*)(sc + e * 4);
        float w[4] = {p.x * inv[0], p.y * inv[1], p.z * inv[2], p.w * inv[3]};
        const float* hs = h + si * 256;
        float* od = out + di * 256;
        #pragma unroll
        for (int j = 0; j < 4; ++j) {
            float hv = hs[j * 64 + lane];
            atomicAdd(od + j * 64 + lane, w[j] * hv);
        }
    }
}

extern "C" void kernel_launch(void* const* d_in, const int* in_sizes, int n_in,
                              void* d_out, int out_size, void* d_ws, size_t ws_size,
                              hipStream_t stream) {
    const float* x   = (const float*)d_in[0];
    const float* W   = (const float*)d_in[1];
    const float* att = (const float*)d_in[2];
    const float* b   = (const float*)d_in[3];
    const int*  eidx = (const int*)d_in[4];
    const int* es = eidx;        // edge_index[0] : sources
    const int* ed = eidx + EE;   // edge_index[1] : destinations
    float* out = (float*)d_out;

    float* h    = (float*)d_ws;              // NN*256
    float* asrc = h + NN * 256;              // NN*4
    float* adst = asrc + NN * 4;             // NN*4
    float* sc   = adst + NN * 4;             // TE*4 (scores then p, in place)
    unsigned* hmax = (unsigned*)(sc + TE * 4);  // 4
    float* hsum = (float*)(hmax + 4);           // 4

    k_init<<<2048, 256, 0, stream>>>(b, out, hmax, hsum);
    k_gemm<<<626, 256, 0, stream>>>(x, W, h);
    k_alpha<<<NN, 256, 0, stream>>>(h, att, asrc, adst);
    k_score<<<(TE + 255) / 256, 256, 0, stream>>>(es, ed, asrc, adst, sc, hmax);
    k_exp<<<(TE + 255) / 256, 256, 0, stream>>>(sc, hmax, hsum);
    k_scatter<<<2560, 256, 0, stream>>>(es, ed, sc, hsum, h, out);
}

// Round 2
// 683.978 us; speedup vs baseline: 1.3030x; 1.3030x over previous
//
#include <hip/hip_runtime.h>

#define NN 20000
#define EE 320000
#define TE 340000   // EE + NN self loops
#define NEG 0.2f
#define SCAN_CH 20  // ceil(20000/1024)

__device__ __forceinline__ unsigned fenc(float x) {
    unsigned b = __float_as_uint(x);
    return (b & 0x80000000u) ? ~b : (b | 0x80000000u);
}
__device__ __forceinline__ float fdec(unsigned u) {
    unsigned b = (u & 0x80000000u) ? (u ^ 0x80000000u) : ~u;
    return __uint_as_float(b);
}
__device__ __forceinline__ float lrelu(float v) { return v > 0.f ? v : NEG * v; }

// ---------------- zero: counts + stats ----------------
__global__ __launch_bounds__(256) void k_zero(int* __restrict__ cnt, unsigned* __restrict__ hmax,
                                              float* __restrict__ hsum) {
    int i = blockIdx.x * 256 + threadIdx.x;
    if (i < NN) cnt[i] = 0;
    if (i < 4) { hmax[i] = 0u; hsum[i] = 0.0f; }
}

// ---------------- fp32 GEMM: h = x @ W  (20000x256 @ 256x256) ----------------
// tile 32 rows x 256 cols, 256 threads; LDS 32KB (x tile); W rows streamed via L1/L2.
// wave = 64 lanes: tx = lane (col4 0..63), ty = wave id (rows ty*8..ty*8+7)
__global__ __launch_bounds__(256) void k_gemm(const float* __restrict__ x, const float* __restrict__ W,
                                              float* __restrict__ h) {
    __shared__ float4 xt4[32][64];   // 32 rows x 256 k, 32 KB
    const int tid = threadIdx.x;
    const int r0 = blockIdx.x * 32;  // 625 blocks * 32 = 20000 exact
    const float4* x4 = (const float4*)x;

    #pragma unroll
    for (int i = 0; i < 8; ++i) {
        int slot = tid + i * 256;    // 2048 float4 slots
        int row = slot >> 6, c4 = slot & 63;
        xt4[row][c4] = x4[(r0 + row) * 64 + c4];
    }
    __syncthreads();

    const int tx = tid & 63, ty = tid >> 6;
    float4 acc[8];
    #pragma unroll
    for (int r = 0; r < 8; ++r) acc[r] = make_float4(0.f, 0.f, 0.f, 0.f);

    const float4* W4 = (const float4*)W;
    for (int k4 = 0; k4 < 64; ++k4) {
        float4 wv[4];
        #pragma unroll
        for (int j = 0; j < 4; ++j) wv[j] = W4[(k4 * 4 + j) * 64 + tx];
        #pragma unroll
        for (int r = 0; r < 8; ++r) {
            float4 xv = xt4[ty * 8 + r][k4];   // wave-uniform -> LDS broadcast
            acc[r].x += xv.x * wv[0].x + xv.y * wv[1].x + xv.z * wv[2].x + xv.w * wv[3].x;
            acc[r].y += xv.x * wv[0].y + xv.y * wv[1].y + xv.z * wv[2].y + xv.w * wv[3].y;
            acc[r].z += xv.x * wv[0].z + xv.y * wv[1].z + xv.z * wv[2].z + xv.w * wv[3].z;
            acc[r].w += xv.x * wv[0].w + xv.y * wv[1].w + xv.z * wv[2].w + xv.w * wv[3].w;
        }
    }

    float4* h4 = (float4*)h;
    #pragma unroll
    for (int r = 0; r < 8; ++r) h4[(r0 + ty * 8 + r) * 64 + tx] = acc[r];
}

// ---------------- per-node attention logits (one wave per node) ----------------
__global__ __launch_bounds__(256) void k_alpha(const float* __restrict__ h, const float* __restrict__ att,
                                               float* __restrict__ asrc, float* __restrict__ adst) {
    int n = blockIdx.x * 4 + (threadIdx.x >> 6);
    int lane = threadIdx.x & 63;
    int head = lane >> 4;
    int off = (lane & 15) * 4;
    float4 v = ((const float4*)h)[n * 64 + lane];
    const float* as = att + head * 128 + off;
    const float* ad = att + head * 128 + 64 + off;
    float l0 = lrelu(v.x), l1 = lrelu(v.y), l2 = lrelu(v.z), l3 = lrelu(v.w);
    float ss = l0 * as[0] + l1 * as[1] + l2 * as[2] + l3 * as[3];
    float sd = l0 * ad[0] + l1 * ad[1] + l2 * ad[2] + l3 * ad[3];
    #pragma unroll
    for (int m = 1; m < 16; m <<= 1) {
        ss += __shfl_xor(ss, m, 64);
        sd += __shfl_xor(sd, m, 64);
    }
    if ((lane & 15) == 0) {
        asrc[n * 4 + head] = ss;
        adst[n * 4 + head] = sd;
    }
}

// ---------------- edge scores + per-head max + dst histogram ----------------
__global__ __launch_bounds__(256) void k_score(const int* __restrict__ es, const int* __restrict__ ed,
                                               const float* __restrict__ asrc, const float* __restrict__ adst,
                                               float* __restrict__ sc, unsigned* __restrict__ hmax,
                                               int* __restrict__ cnt) {
    int e = blockIdx.x * 256 + threadIdx.x;
    float4 s = {-1e30f, -1e30f, -1e30f, -1e30f};
    if (e < TE) {
        int si = e < EE ? es[e] : e - EE;
        int di = e < EE ? ed[e] : e - EE;
        float4 a = *(const float4*)(asrc + si * 4);
        float4 b = *(const float4*)(adst + di * 4);
        s.x = a.x + b.x; s.y = a.y + b.y; s.z = a.z + b.z; s.w = a.w + b.w;
        *(float4*)(sc + e * 4) = s;
        atomicAdd(cnt + di, 1);
    }
    float m0 = s.x, m1 = s.y, m2 = s.z, m3 = s.w;
    #pragma unroll
    for (int m = 32; m > 0; m >>= 1) {
        m0 = fmaxf(m0, __shfl_xor(m0, m, 64));
        m1 = fmaxf(m1, __shfl_xor(m1, m, 64));
        m2 = fmaxf(m2, __shfl_xor(m2, m, 64));
        m3 = fmaxf(m3, __shfl_xor(m3, m, 64));
    }
    if ((threadIdx.x & 63) == 0) {
        atomicMax(hmax + 0, fenc(m0));
        atomicMax(hmax + 1, fenc(m1));
        atomicMax(hmax + 2, fenc(m2));
        atomicMax(hmax + 3, fenc(m3));
    }
}

// ---------------- single-block exclusive scan of cnt -> offs, cursor ----------------
__global__ __launch_bounds__(1024) void k_scan(const int* __restrict__ cnt, int* __restrict__ offs,
                                               int* __restrict__ cursor) {
    __shared__ int wsum[16];
    int tid = threadIdx.x;
    int base = tid * SCAN_CH;
    int loc[SCAN_CH];
    int sum = 0;
    #pragma unroll
    for (int i = 0; i < SCAN_CH; ++i) {
        int idx = base + i;
        int v = (idx < NN) ? cnt[idx] : 0;
        loc[i] = sum;
        sum += v;
    }
    int v = sum;
    #pragma unroll
    for (int off = 1; off < 64; off <<= 1) {
        int t = __shfl_up(v, off, 64);
        if ((tid & 63) >= off) v += t;
    }
    if ((tid & 63) == 63) wsum[tid >> 6] = v;
    __syncthreads();
    if (tid < 16) {
        int w = wsum[tid];
        #pragma unroll
        for (int off = 1; off < 16; off <<= 1) {
            int t = __shfl_up(w, off, 16);
            if (tid >= off) w += t;
        }
        wsum[tid] = w;
    }
    __syncthreads();
    int wid = tid >> 6;
    int waveoff = (wid == 0) ? 0 : wsum[wid - 1];
    int excl = waveoff + v - sum;   // exclusive prefix for this thread's chunk
    #pragma unroll
    for (int i = 0; i < SCAN_CH; ++i) {
        int idx = base + i;
        if (idx < NN) { int o = excl + loc[i]; offs[idx] = o; cursor[idx] = o; }
    }
    if (tid == 1023) offs[NN] = waveoff + v;  // == TE
}

// ---------------- bucket fill: (src, edge-id) per dst bin ----------------
__global__ __launch_bounds__(256) void k_fill(const int* __restrict__ es, const int* __restrict__ ed,
                                              int* __restrict__ cursor, int2* __restrict__ bucket) {
    int e = blockIdx.x * 256 + threadIdx.x;
    if (e >= TE) return;
    int si = e < EE ? es[e] : e - EE;
    int di = e < EE ? ed[e] : e - EE;
    int pos = atomicAdd(cursor + di, 1);
    bucket[pos] = make_int2(si, e);
}

// ---------------- per-head sum of exp(s - max) (reduction only) ----------------
__global__ __launch_bounds__(256) void k_sum(const float* __restrict__ sc, const unsigned* __restrict__ hmax,
                                             float* __restrict__ hsum) {
    int e = blockIdx.x * 256 + threadIdx.x;
    float mx0 = fdec(hmax[0]), mx1 = fdec(hmax[1]), mx2 = fdec(hmax[2]), mx3 = fdec(hmax[3]);
    float p0 = 0.f, p1 = 0.f, p2 = 0.f, p3 = 0.f;
    if (e < TE) {
        float4 s = *(const float4*)(sc + e * 4);
        p0 = expf(s.x - mx0); p1 = expf(s.y - mx1);
        p2 = expf(s.z - mx2); p3 = expf(s.w - mx3);
    }
    #pragma unroll
    for (int m = 32; m > 0; m >>= 1) {
        p0 += __shfl_xor(p0, m, 64);
        p1 += __shfl_xor(p1, m, 64);
        p2 += __shfl_xor(p2, m, 64);
        p3 += __shfl_xor(p3, m, 64);
    }
    if ((threadIdx.x & 63) == 0) {
        atomicAdd(hsum + 0, p0);
        atomicAdd(hsum + 1, p1);
        atomicAdd(hsum + 2, p2);
        atomicAdd(hsum + 3, p3);
    }
}

// ---------------- gather: out[n] = b + sum_{e in bin(n)} w_e * h[src_e] ----------------
// one wave per dst node; lane covers 4 contiguous dims (all in one head)
__global__ __launch_bounds__(256) void k_gather(const int* __restrict__ offs, const int2* __restrict__ bucket,
                                                const float* __restrict__ sc, const unsigned* __restrict__ hmax,
                                                const float* __restrict__ hsum, const float* __restrict__ h,
                                                const float* __restrict__ b, float* __restrict__ out) {
    int n = blockIdx.x * 4 + (threadIdx.x >> 6);
    int lane = threadIdx.x & 63;
    int head = lane >> 4;
    float mx = fdec(hmax[head]);
    float invZ = 1.0f / hsum[head];
    int beg = offs[n], end = offs[n + 1];
    const float4* h4 = (const float4*)h;
    float4 acc = make_float4(0.f, 0.f, 0.f, 0.f);
    for (int j = beg; j < end; ++j) {
        int2 se = bucket[j];                      // wave-uniform -> broadcast
        float s = sc[se.y * 4 + head];
        float w = expf(s - mx) * invZ;
        float4 hv = h4[se.x * 64 + lane];         // coalesced 1KB per edge
        acc.x += w * hv.x; acc.y += w * hv.y; acc.z += w * hv.z; acc.w += w * hv.w;
    }
    float4 bb = ((const float4*)b)[lane];
    acc.x += bb.x; acc.y += bb.y; acc.z += bb.z; acc.w += bb.w;
    ((float4*)out)[n * 64 + lane] = acc;
}

extern "C" void kernel_launch(void* const* d_in, const int* in_sizes, int n_in,
                              void* d_out, int out_size, void* d_ws, size_t ws_size,
                              hipStream_t stream) {
    const float* x   = (const float*)d_in[0];
    const float* W   = (const float*)d_in[1];
    const float* att = (const float*)d_in[2];
    const float* b   = (const float*)d_in[3];
    const int*  eidx = (const int*)d_in[4];
    const int* es = eidx;        // edge_index[0] : sources
    const int* ed = eidx + EE;   // edge_index[1] : destinations
    float* out = (float*)d_out;

    float* ws = (float*)d_ws;
    float* h     = ws;                         // 5,120,000 f
    float* asrc  = h + NN * 256;               // 80,000 f
    float* adst  = asrc + NN * 4;              // 80,000 f
    float* sc    = adst + NN * 4;              // 1,360,000 f
    int*   cnt   = (int*)(sc + TE * 4);        // 20,000 i
    int*   offs  = cnt + NN;                   // 20,004 i (padded, keeps 8B align)
    int*   cursor= offs + NN + 4;              // 20,000 i
    int2*  bucket= (int2*)(cursor + NN);       // 340,000 int2 (8B-aligned)
    unsigned* hmax = (unsigned*)(bucket + TE); // 4
    float* hsum  = (float*)(hmax + 4);         // 4

    k_zero  <<<(NN + 255) / 256, 256, 0, stream>>>(cnt, hmax, hsum);
    k_gemm  <<<NN / 32, 256, 0, stream>>>(x, W, h);
    k_alpha <<<NN / 4, 256, 0, stream>>>(h, att, asrc, adst);
    k_score <<<(TE + 255) / 256, 256, 0, stream>>>(es, ed, asrc, adst, sc, hmax, cnt);
    k_scan  <<<1, 1024, 0, stream>>>(cnt, offs, cursor);
    k_fill  <<<(TE + 255) / 256, 256, 0, stream>>>(es, ed, cursor, bucket);
    k_sum   <<<(TE + 255) / 256, 256, 0, stream>>>(sc, hmax, hsum);
    k_gather<<<NN / 4, 256, 0, stream>>>(offs, bucket, sc, hmax, hsum, h, b, out);
}

// Round 3
// 178.702 us; speedup vs baseline: 4.9871x; 3.8275x over previous
//
#include <hip/hip_runtime.h>

#define NN 20000
#define EE 320000
#define TE 340000        // EE + NN self loops
#define NEG 0.2f
#define NB_SCORE 1329    // ceil(TE/256)
#define SCAN_CH 20       // ceil(20000/1024)

__device__ __forceinline__ float lrelu(float v) { return v > 0.f ? v : NEG * v; }

// ---------------- zero: dst histogram ----------------
__global__ __launch_bounds__(256) void k_zero(int* __restrict__ cnt) {
    int i = blockIdx.x * 256 + threadIdx.x;
    if (i < NN) cnt[i] = 0;
}

// ---------------- fp32 GEMM: h = x @ W  (+ fused alpha epilogue) ----------------
// tile 32 rows x 256 cols, 256 threads; LDS 32KB (x tile); W rows streamed via L2.
// wave = 64 lanes: tx = lane (col4 0..63), ty = wave id (rows ty*8..ty*8+7)
__global__ __launch_bounds__(256) void k_gemm(const float* __restrict__ x, const float* __restrict__ W,
                                              const float* __restrict__ att, float* __restrict__ h,
                                              float* __restrict__ asrc, float* __restrict__ adst) {
    __shared__ float4 xt4[32][64];   // 32 rows x 256 k, 32 KB
    const int tid = threadIdx.x;
    const int r0 = blockIdx.x * 32;  // 625 blocks * 32 = 20000 exact
    const float4* x4 = (const float4*)x;

    #pragma unroll
    for (int i = 0; i < 8; ++i) {
        int slot = tid + i * 256;    // 2048 float4 slots
        int row = slot >> 6, c4 = slot & 63;
        xt4[row][c4] = x4[(r0 + row) * 64 + c4];
    }
    __syncthreads();

    const int tx = tid & 63, ty = tid >> 6;
    const int head = tx >> 4;
    float4 acc[8];
    #pragma unroll
    for (int r = 0; r < 8; ++r) acc[r] = make_float4(0.f, 0.f, 0.f, 0.f);

    const float4* W4 = (const float4*)W;
    for (int k4 = 0; k4 < 64; ++k4) {
        float4 wv[4];
        #pragma unroll
        for (int j = 0; j < 4; ++j) wv[j] = W4[(k4 * 4 + j) * 64 + tx];
        #pragma unroll
        for (int r = 0; r < 8; ++r) {
            float4 xv = xt4[ty * 8 + r][k4];   // wave-uniform -> LDS broadcast
            acc[r].x += xv.x * wv[0].x + xv.y * wv[1].x + xv.z * wv[2].x + xv.w * wv[3].x;
            acc[r].y += xv.x * wv[0].y + xv.y * wv[1].y + xv.z * wv[2].y + xv.w * wv[3].y;
            acc[r].z += xv.x * wv[0].z + xv.y * wv[1].z + xv.z * wv[2].z + xv.w * wv[3].z;
            acc[r].w += xv.x * wv[0].w + xv.y * wv[1].w + xv.z * wv[2].w + xv.w * wv[3].w;
        }
    }

    // att fragments for this thread's 4 dims: d = (tx&15)*4 .. +3 of head
    float4 av = ((const float4*)att)[head * 32 + (tx & 15)];        // a_src
    float4 dv = ((const float4*)att)[head * 32 + 16 + (tx & 15)];   // a_dst

    float4* h4 = (float4*)h;
    #pragma unroll
    for (int r = 0; r < 8; ++r) {
        int g = r0 + ty * 8 + r;
        h4[g * 64 + tx] = acc[r];
        float l0 = lrelu(acc[r].x), l1 = lrelu(acc[r].y), l2 = lrelu(acc[r].z), l3 = lrelu(acc[r].w);
        float ss = l0 * av.x + l1 * av.y + l2 * av.z + l3 * av.w;
        float sd = l0 * dv.x + l1 * dv.y + l2 * dv.z + l3 * dv.w;
        #pragma unroll
        for (int m = 1; m < 16; m <<= 1) {
            ss += __shfl_xor(ss, m, 64);
            sd += __shfl_xor(sd, m, 64);
        }
        if ((tx & 15) == 0) {
            asrc[g * 4 + head] = ss;
            adst[g * 4 + head] = sd;
        }
    }
}

// ---------------- edge scores: per-block (max, sum-of-exp) partials + dst histogram ----------------
__global__ __launch_bounds__(256) void k_score(const int* __restrict__ es, const int* __restrict__ ed,
                                               const float* __restrict__ asrc, const float* __restrict__ adst,
                                               float4* __restrict__ pmax, float4* __restrict__ psum,
                                               int* __restrict__ cnt) {
    int e = blockIdx.x * 256 + threadIdx.x;
    int tid = threadIdx.x, lane = tid & 63, wid = tid >> 6;
    float4 s = {-1e30f, -1e30f, -1e30f, -1e30f};
    bool act = e < TE;
    if (act) {
        int si = e < EE ? es[e] : e - EE;
        int di = e < EE ? ed[e] : e - EE;
        float4 a = *(const float4*)(asrc + si * 4);
        float4 b = *(const float4*)(adst + di * 4);
        s.x = a.x + b.x; s.y = a.y + b.y; s.z = a.z + b.z; s.w = a.w + b.w;
        atomicAdd(cnt + di, 1);
    }
    // wave max per head
    float m0 = s.x, m1 = s.y, m2 = s.z, m3 = s.w;
    #pragma unroll
    for (int m = 32; m > 0; m >>= 1) {
        m0 = fmaxf(m0, __shfl_xor(m0, m, 64));
        m1 = fmaxf(m1, __shfl_xor(m1, m, 64));
        m2 = fmaxf(m2, __shfl_xor(m2, m, 64));
        m3 = fmaxf(m3, __shfl_xor(m3, m, 64));
    }
    __shared__ float4 lm[4];
    if (lane == 0) lm[wid] = make_float4(m0, m1, m2, m3);
    __syncthreads();
    float4 bm;
    bm.x = fmaxf(fmaxf(lm[0].x, lm[1].x), fmaxf(lm[2].x, lm[3].x));
    bm.y = fmaxf(fmaxf(lm[0].y, lm[1].y), fmaxf(lm[2].y, lm[3].y));
    bm.z = fmaxf(fmaxf(lm[0].z, lm[1].z), fmaxf(lm[2].z, lm[3].z));
    bm.w = fmaxf(fmaxf(lm[0].w, lm[1].w), fmaxf(lm[2].w, lm[3].w));
    // partial sums of exp(s - block_max)
    float p0 = act ? expf(s.x - bm.x) : 0.f;
    float p1 = act ? expf(s.y - bm.y) : 0.f;
    float p2 = act ? expf(s.z - bm.z) : 0.f;
    float p3 = act ? expf(s.w - bm.w) : 0.f;
    #pragma unroll
    for (int m = 32; m > 0; m >>= 1) {
        p0 += __shfl_xor(p0, m, 64);
        p1 += __shfl_xor(p1, m, 64);
        p2 += __shfl_xor(p2, m, 64);
        p3 += __shfl_xor(p3, m, 64);
    }
    __shared__ float4 ls[4];
    if (lane == 0) ls[wid] = make_float4(p0, p1, p2, p3);
    __syncthreads();
    if (tid == 0) {
        float4 t;
        t.x = ls[0].x + ls[1].x + ls[2].x + ls[3].x;
        t.y = ls[0].y + ls[1].y + ls[2].y + ls[3].y;
        t.z = ls[0].z + ls[1].z + ls[2].z + ls[3].z;
        t.w = ls[0].w + ls[1].w + ls[2].w + ls[3].w;
        pmax[blockIdx.x] = bm;
        psum[blockIdx.x] = t;
    }
}

// ---------------- combine partials: M = max m_b; Z = sum exp(m_b - M) * S_b ----------------
__global__ __launch_bounds__(256) void k_combine(const float4* __restrict__ pmax,
                                                 const float4* __restrict__ psum,
                                                 float* __restrict__ hstat) {
    int tid = threadIdx.x, lane = tid & 63, wid = tid >> 6;
    float4 m = {-1e30f, -1e30f, -1e30f, -1e30f};
    for (int i = tid; i < NB_SCORE; i += 256) {
        float4 v = pmax[i];
        m.x = fmaxf(m.x, v.x); m.y = fmaxf(m.y, v.y);
        m.z = fmaxf(m.z, v.z); m.w = fmaxf(m.w, v.w);
    }
    #pragma unroll
    for (int o = 32; o > 0; o >>= 1) {
        m.x = fmaxf(m.x, __shfl_xor(m.x, o, 64));
        m.y = fmaxf(m.y, __shfl_xor(m.y, o, 64));
        m.z = fmaxf(m.z, __shfl_xor(m.z, o, 64));
        m.w = fmaxf(m.w, __shfl_xor(m.w, o, 64));
    }
    __shared__ float4 sm[4];
    if (lane == 0) sm[wid] = m;
    __syncthreads();
    float4 M;
    M.x = fmaxf(fmaxf(sm[0].x, sm[1].x), fmaxf(sm[2].x, sm[3].x));
    M.y = fmaxf(fmaxf(sm[0].y, sm[1].y), fmaxf(sm[2].y, sm[3].y));
    M.z = fmaxf(fmaxf(sm[0].z, sm[1].z), fmaxf(sm[2].z, sm[3].z));
    M.w = fmaxf(fmaxf(sm[0].w, sm[1].w), fmaxf(sm[2].w, sm[3].w));
    float4 z = {0.f, 0.f, 0.f, 0.f};
    for (int i = tid; i < NB_SCORE; i += 256) {
        float4 v = pmax[i], s = psum[i];
        z.x += expf(v.x - M.x) * s.x;
        z.y += expf(v.y - M.y) * s.y;
        z.z += expf(v.z - M.z) * s.z;
        z.w += expf(v.w - M.w) * s.w;
    }
    #pragma unroll
    for (int o = 32; o > 0; o >>= 1) {
        z.x += __shfl_xor(z.x, o, 64);
        z.y += __shfl_xor(z.y, o, 64);
        z.z += __shfl_xor(z.z, o, 64);
        z.w += __shfl_xor(z.w, o, 64);
    }
    __syncthreads();   // sm reuse
    if (lane == 0) sm[wid] = z;
    __syncthreads();
    if (tid == 0) {
        hstat[0] = M.x; hstat[1] = M.y; hstat[2] = M.z; hstat[3] = M.w;
        hstat[4] = sm[0].x + sm[1].x + sm[2].x + sm[3].x;
        hstat[5] = sm[0].y + sm[1].y + sm[2].y + sm[3].y;
        hstat[6] = sm[0].z + sm[1].z + sm[2].z + sm[3].z;
        hstat[7] = sm[0].w + sm[1].w + sm[2].w + sm[3].w;
    }
}

// ---------------- single-block exclusive scan of cnt -> offs, cursor ----------------
__global__ __launch_bounds__(1024) void k_scan(const int* __restrict__ cnt, int* __restrict__ offs,
                                               int* __restrict__ cursor) {
    __shared__ int wsum[16];
    int tid = threadIdx.x;
    int base = tid * SCAN_CH;
    int loc[SCAN_CH];
    int sum = 0;
    #pragma unroll
    for (int i = 0; i < SCAN_CH; ++i) {
        int idx = base + i;
        int v = (idx < NN) ? cnt[idx] : 0;
        loc[i] = sum;
        sum += v;
    }
    int v = sum;
    #pragma unroll
    for (int off = 1; off < 64; off <<= 1) {
        int t = __shfl_up(v, off, 64);
        if ((tid & 63) >= off) v += t;
    }
    if ((tid & 63) == 63) wsum[tid >> 6] = v;
    __syncthreads();
    if (tid < 16) {
        int w = wsum[tid];
        #pragma unroll
        for (int off = 1; off < 16; off <<= 1) {
            int t = __shfl_up(w, off, 16);
            if (tid >= off) w += t;
        }
        wsum[tid] = w;
    }
    __syncthreads();
    int wid = tid >> 6;
    int waveoff = (wid == 0) ? 0 : wsum[wid - 1];
    int excl = waveoff + v - sum;   // exclusive prefix for this thread's chunk
    #pragma unroll
    for (int i = 0; i < SCAN_CH; ++i) {
        int idx = base + i;
        if (idx < NN) { int o = excl + loc[i]; offs[idx] = o; cursor[idx] = o; }
    }
    if (tid == 1023) offs[NN] = waveoff + v;  // == TE
}

// ---------------- bucket fill: src per dst bin ----------------
__global__ __launch_bounds__(256) void k_fill(const int* __restrict__ es, const int* __restrict__ ed,
                                              int* __restrict__ cursor, int* __restrict__ bucket) {
    int e = blockIdx.x * 256 + threadIdx.x;
    if (e >= TE) return;
    int si = e < EE ? es[e] : e - EE;
    int di = e < EE ? ed[e] : e - EE;
    int pos = atomicAdd(cursor + di, 1);
    bucket[pos] = si;
}

// ---------------- gather: out[n] = b + sum_{e in bin(n)} softmax_w * h[src_e] ----------------
// one wave per dst node; lane covers 4 contiguous dims (all in one head)
__global__ __launch_bounds__(256) void k_gather(const int* __restrict__ offs, const int* __restrict__ bucket,
                                                const float* __restrict__ asrc, const float* __restrict__ adst,
                                                const float* __restrict__ hstat, const float* __restrict__ h,
                                                const float* __restrict__ b, float* __restrict__ out) {
    int n = blockIdx.x * 4 + (threadIdx.x >> 6);
    int lane = threadIdx.x & 63;
    int head = lane >> 4;
    float mx = hstat[head];
    float invZ = 1.0f / hstat[4 + head];
    float base = adst[n * 4 + head] - mx;   // wave-uniform per head
    int beg = offs[n], end = offs[n + 1];
    const float4* h4 = (const float4*)h;
    float4 acc = make_float4(0.f, 0.f, 0.f, 0.f);
    int si = (beg < end) ? bucket[beg] : 0;
    for (int j = beg; j < end; ++j) {
        int si_n = (j + 1 < end) ? bucket[j + 1] : 0;   // prefetch next index
        float sa = asrc[si * 4 + head];
        float4 hv = h4[si * 64 + lane];                 // coalesced 1KB per edge
        float w = expf(sa + base) * invZ;
        acc.x += w * hv.x; acc.y += w * hv.y; acc.z += w * hv.z; acc.w += w * hv.w;
        si = si_n;
    }
    float4 bb = ((const float4*)b)[lane];
    acc.x += bb.x; acc.y += bb.y; acc.z += bb.z; acc.w += bb.w;
    ((float4*)out)[n * 64 + lane] = acc;
}

extern "C" void kernel_launch(void* const* d_in, const int* in_sizes, int n_in,
                              void* d_out, int out_size, void* d_ws, size_t ws_size,
                              hipStream_t stream) {
    const float* x   = (const float*)d_in[0];
    const float* W   = (const float*)d_in[1];
    const float* att = (const float*)d_in[2];
    const float* b   = (const float*)d_in[3];
    const int*  eidx = (const int*)d_in[4];
    const int* es = eidx;        // edge_index[0] : sources
    const int* ed = eidx + EE;   // edge_index[1] : destinations
    float* out = (float*)d_out;

    float* ws = (float*)d_ws;
    float* h      = ws;                        // 5,120,000 f
    float* asrc   = h + NN * 256;              // 80,000 f
    float* adst   = asrc + NN * 4;             // 80,000 f
    int*   cnt    = (int*)(adst + NN * 4);     // 20,000 i
    int*   offs   = cnt + NN;                  // 20,008 i (incl. sentinel + pad)
    int*   cursor = offs + NN + 8;             // 20,000 i
    int*   bucket = cursor + NN;               // 340,000 i
    float4* pmax  = (float4*)(bucket + TE);    // NB_SCORE f4
    float4* psum  = pmax + NB_SCORE;           // NB_SCORE f4
    float* hstat  = (float*)(psum + NB_SCORE); // 8 f  (max[4], sum[4])

    k_zero   <<<(NN + 255) / 256, 256, 0, stream>>>(cnt);
    k_gemm   <<<NN / 32, 256, 0, stream>>>(x, W, att, h, asrc, adst);
    k_score  <<<NB_SCORE, 256, 0, stream>>>(es, ed, asrc, adst, pmax, psum, cnt);
    k_scan   <<<1, 1024, 0, stream>>>(cnt, offs, cursor);
    k_fill   <<<(TE + 255) / 256, 256, 0, stream>>>(es, ed, cursor, bucket);
    k_combine<<<1, 256, 0, stream>>>(pmax, psum, hstat);
    k_gather <<<NN / 4, 256, 0, stream>>>(offs, bucket, asrc, adst, hstat, h, b, out);
}

// Round 4
// 174.426 us; speedup vs baseline: 5.1093x; 1.0245x over previous
//
#include <hip/hip_runtime.h>

#define NN 20000
#define EE 320000
#define TE 340000        // EE + NN self loops
#define NEG 0.2f
#define NB_SCORE 1329    // ceil(TE/256)
#define NB_GEMM 1250     // 20000 / 16
#define SCAN_CH 20       // ceil(20000/1024)

__device__ __forceinline__ float lrelu(float v) { return v > 0.f ? v : NEG * v; }

// ---------------- fp32 GEMM: h = x @ W (+ alpha epilogue + per-block alpha max + cnt zero) ----------------
// tile 16 rows x 256 cols, 256 threads (4 waves, 4 rows/wave); LDS 16KB; W double-buffered in regs.
__global__ __launch_bounds__(256, 4) void k_gemm(const float* __restrict__ x, const float* __restrict__ W,
                                                 const float* __restrict__ att, float* __restrict__ h,
                                                 float* __restrict__ as, float* __restrict__ ad,
                                                 float* __restrict__ bmaxT, int* __restrict__ cnt) {
    __shared__ float4 xt4[16][64];   // 16 rows x 256 k = 16 KB
    __shared__ float smax[4][8];
    const int tid = threadIdx.x;
    const int r0 = blockIdx.x * 16;
    const float4* x4 = (const float4*)x;

    if (tid < 16) cnt[r0 + tid] = 0;   // fold histogram zeroing (consumed by k_score, after this kernel)

    #pragma unroll
    for (int i = 0; i < 4; ++i) {
        int slot = tid + i * 256;      // 1024 float4 slots
        xt4[slot >> 6][slot & 63] = x4[(r0 + (slot >> 6)) * 64 + (slot & 63)];
    }
    __syncthreads();

    const int tx = tid & 63, ty = tid >> 6;
    const int head = tx >> 4, sub = tx & 15;
    float4 acc[4];
    #pragma unroll
    for (int r = 0; r < 4; ++r) acc[r] = make_float4(0.f, 0.f, 0.f, 0.f);

    const float4* W4 = (const float4*)W;
    auto fma4 = [&](const float4* wv, int k4) {
        #pragma unroll
        for (int r = 0; r < 4; ++r) {
            float4 xv = xt4[ty * 4 + r][k4];   // wave-uniform -> LDS broadcast
            acc[r].x += xv.x * wv[0].x + xv.y * wv[1].x + xv.z * wv[2].x + xv.w * wv[3].x;
            acc[r].y += xv.x * wv[0].y + xv.y * wv[1].y + xv.z * wv[2].y + xv.w * wv[3].y;
            acc[r].z += xv.x * wv[0].z + xv.y * wv[1].z + xv.z * wv[2].z + xv.w * wv[3].z;
            acc[r].w += xv.x * wv[0].w + xv.y * wv[1].w + xv.z * wv[2].w + xv.w * wv[3].w;
        }
    };

    float4 wv[4], wn[4];
    #pragma unroll
    for (int j = 0; j < 4; ++j) wv[j] = W4[j * 64 + tx];
    #pragma unroll 2
    for (int k4 = 0; k4 < 63; ++k4) {
        #pragma unroll
        for (int j = 0; j < 4; ++j) wn[j] = W4[((k4 + 1) * 4 + j) * 64 + tx];
        fma4(wv, k4);
        #pragma unroll
        for (int j = 0; j < 4; ++j) wv[j] = wn[j];
    }
    fma4(wv, 63);

    // epilogue: h store + alpha_src/dst (16-lane reduce) + running per-wave max
    float4 av = ((const float4*)att)[head * 32 + sub];        // a_src coefs
    float4 dv = ((const float4*)att)[head * 32 + 16 + sub];   // a_dst coefs
    float mxs = -1e30f, mxd = -1e30f;
    float4* h4 = (float4*)h;
    #pragma unroll
    for (int r = 0; r < 4; ++r) {
        int g = r0 + ty * 4 + r;
        h4[g * 64 + tx] = acc[r];
        float l0 = lrelu(acc[r].x), l1 = lrelu(acc[r].y), l2 = lrelu(acc[r].z), l3 = lrelu(acc[r].w);
        float ss = l0 * av.x + l1 * av.y + l2 * av.z + l3 * av.w;
        float sd = l0 * dv.x + l1 * dv.y + l2 * dv.z + l3 * dv.w;
        #pragma unroll
        for (int m = 1; m < 16; m <<= 1) {
            ss += __shfl_xor(ss, m, 64);
            sd += __shfl_xor(sd, m, 64);
        }
        if (sub == 0) {
            as[g * 4 + head] = ss;
            ad[g * 4 + head] = sd;
            mxs = fmaxf(mxs, ss);
            mxd = fmaxf(mxd, sd);
        }
    }
    if (sub == 0) { smax[ty][head] = mxs; smax[ty][4 + head] = mxd; }
    __syncthreads();
    if (tid < 8) {
        float m = fmaxf(fmaxf(smax[0][tid], smax[1][tid]), fmaxf(smax[2][tid], smax[3][tid]));
        bmaxT[tid * 1280 + blockIdx.x] = m;   // transposed layout for coalesced reduce
    }
}

// ---------------- Es = exp(asrc - Ma), Ed = exp(adst - Md) in place ----------------
__global__ __launch_bounds__(256) void k_escale(const float* __restrict__ bmaxT,
                                                float* __restrict__ as, float* __restrict__ ad) {
    __shared__ float M[8];
    int tid = threadIdx.x;
    int g = tid >> 5, l = tid & 31;     // 8 groups of 32 threads; group g reduces col g
    float m = -1e30f;
    for (int i = l; i < NB_GEMM; i += 32) m = fmaxf(m, bmaxT[g * 1280 + i]);
    #pragma unroll
    for (int s = 16; s > 0; s >>= 1) m = fmaxf(m, __shfl_xor(m, s, 32));
    if (l == 0) M[g] = m;
    __syncthreads();
    int n = blockIdx.x * 256 + tid;
    if (n < NN) {
        float4 a = ((float4*)as)[n];
        a.x = expf(a.x - M[0]); a.y = expf(a.y - M[1]);
        a.z = expf(a.z - M[2]); a.w = expf(a.w - M[3]);
        ((float4*)as)[n] = a;
        float4 d = ((float4*)ad)[n];
        d.x = expf(d.x - M[4]); d.y = expf(d.y - M[5]);
        d.z = expf(d.z - M[6]); d.w = expf(d.w - M[7]);
        ((float4*)ad)[n] = d;
    }
}

// ---------------- per-edge p = Es[si]*Ed[di]: block partial sums + dst histogram ----------------
__global__ __launch_bounds__(256) void k_score(const int* __restrict__ es, const int* __restrict__ ed,
                                               const float* __restrict__ Es, const float* __restrict__ Ed,
                                               float4* __restrict__ psum, int* __restrict__ cnt) {
    __shared__ float4 ls[4];
    int e = blockIdx.x * 256 + threadIdx.x;
    int tid = threadIdx.x, lane = tid & 63, wid = tid >> 6;
    float4 p = {0.f, 0.f, 0.f, 0.f};
    if (e < TE) {
        int si = e < EE ? es[e] : e - EE;
        int di = e < EE ? ed[e] : e - EE;
        float4 a = ((const float4*)Es)[si];
        float4 d = ((const float4*)Ed)[di];
        p.x = a.x * d.x; p.y = a.y * d.y; p.z = a.z * d.z; p.w = a.w * d.w;
        atomicAdd(cnt + di, 1);
    }
    #pragma unroll
    for (int m = 32; m > 0; m >>= 1) {
        p.x += __shfl_xor(p.x, m, 64);
        p.y += __shfl_xor(p.y, m, 64);
        p.z += __shfl_xor(p.z, m, 64);
        p.w += __shfl_xor(p.w, m, 64);
    }
    if (lane == 0) ls[wid] = p;
    __syncthreads();
    if (tid == 0) {
        float4 t;
        t.x = ls[0].x + ls[1].x + ls[2].x + ls[3].x;
        t.y = ls[0].y + ls[1].y + ls[2].y + ls[3].y;
        t.z = ls[0].z + ls[1].z + ls[2].z + ls[3].z;
        t.w = ls[0].w + ls[1].w + ls[2].w + ls[3].w;
        psum[blockIdx.x] = t;
    }
}

// ---------------- scan cnt -> offs/cursor, then Z = sum psum -> invZ ----------------
__global__ __launch_bounds__(1024) void k_scanc(const int* __restrict__ cnt, int* __restrict__ offs,
                                                int* __restrict__ cursor, const float4* __restrict__ psum,
                                                float* __restrict__ hstat) {
    __shared__ int wsum[16];
    __shared__ float4 zred[16];
    int tid = threadIdx.x, lane = tid & 63, wid = tid >> 6;
    int base = tid * SCAN_CH;
    int loc[SCAN_CH];
    int sum = 0;
    #pragma unroll
    for (int i = 0; i < SCAN_CH; ++i) {
        int idx = base + i;
        int v = (idx < NN) ? cnt[idx] : 0;
        loc[i] = sum;
        sum += v;
    }
    int v = sum;
    #pragma unroll
    for (int off = 1; off < 64; off <<= 1) {
        int t = __shfl_up(v, off, 64);
        if (lane >= off) v += t;
    }
    if (lane == 63) wsum[wid] = v;
    __syncthreads();
    if (tid < 16) {
        int w = wsum[tid];
        #pragma unroll
        for (int off = 1; off < 16; off <<= 1) {
            int t = __shfl_up(w, off, 16);
            if (tid >= off) w += t;
        }
        wsum[tid] = w;
    }
    __syncthreads();
    int waveoff = (wid == 0) ? 0 : wsum[wid - 1];
    int excl = waveoff + v - sum;
    #pragma unroll
    for (int i = 0; i < SCAN_CH; ++i) {
        int idx = base + i;
        if (idx < NN) { int o = excl + loc[i]; offs[idx] = o; cursor[idx] = o; }
    }
    if (tid == 1023) offs[NN] = waveoff + v;   // == TE

    // ---- Z combine ----
    float4 z = {0.f, 0.f, 0.f, 0.f};
    for (int i = tid; i < NB_SCORE; i += 1024) {
        float4 s = psum[i];
        z.x += s.x; z.y += s.y; z.z += s.z; z.w += s.w;
    }
    #pragma unroll
    for (int m = 32; m > 0; m >>= 1) {
        z.x += __shfl_xor(z.x, m, 64);
        z.y += __shfl_xor(z.y, m, 64);
        z.z += __shfl_xor(z.z, m, 64);
        z.w += __shfl_xor(z.w, m, 64);
    }
    if (lane == 0) zred[wid] = z;
    __syncthreads();
    if (tid == 0) {
        float4 t = {0.f, 0.f, 0.f, 0.f};
        #pragma unroll
        for (int i = 0; i < 16; ++i) {
            t.x += zred[i].x; t.y += zred[i].y; t.z += zred[i].z; t.w += zred[i].w;
        }
        hstat[0] = 1.0f / t.x; hstat[1] = 1.0f / t.y;
        hstat[2] = 1.0f / t.z; hstat[3] = 1.0f / t.w;
    }
}

// ---------------- bucket fill: (src, normalized weight4) per dst bin ----------------
__global__ __launch_bounds__(256) void k_fill(const int* __restrict__ es, const int* __restrict__ ed,
                                              const float* __restrict__ Es, const float* __restrict__ Ed,
                                              const float* __restrict__ hstat, int* __restrict__ cursor,
                                              int* __restrict__ bsi, float4* __restrict__ bw) {
    int e = blockIdx.x * 256 + threadIdx.x;
    if (e >= TE) return;
    int si = e < EE ? es[e] : e - EE;
    int di = e < EE ? ed[e] : e - EE;
    float4 a = ((const float4*)Es)[si];
    float4 d = ((const float4*)Ed)[di];
    float4 iz = *((const float4*)hstat);
    float4 w = {a.x * d.x * iz.x, a.y * d.y * iz.y, a.z * d.z * iz.z, a.w * d.w * iz.w};
    int pos = atomicAdd(cursor + di, 1);
    bsi[pos] = si;
    bw[pos] = w;
}

// ---------------- gather: out[n] = b + sum_{e in bin(n)} w_e * h[src_e] ----------------
// one wave per dst node; unroll x4 with 4 accumulators for memory-level parallelism
__global__ __launch_bounds__(256) void k_gather(const int* __restrict__ offs, const int* __restrict__ bsi,
                                                const float* __restrict__ bw, const float* __restrict__ h,
                                                const float* __restrict__ b, float* __restrict__ out) {
    int n = blockIdx.x * 4 + (threadIdx.x >> 6);
    int lane = threadIdx.x & 63;
    int head = lane >> 4;
    int beg = offs[n], end = offs[n + 1];
    const float4* h4 = (const float4*)h;
    float4 a0 = {0.f, 0.f, 0.f, 0.f}, a1 = a0, a2 = a0, a3 = a0;
    int j = beg;
    for (; j + 3 < end; j += 4) {
        int s0 = bsi[j], s1 = bsi[j + 1], s2 = bsi[j + 2], s3 = bsi[j + 3];
        float w0 = bw[j * 4 + head], w1 = bw[j * 4 + 4 + head];
        float w2 = bw[j * 4 + 8 + head], w3 = bw[j * 4 + 12 + head];
        float4 h0 = h4[s0 * 64 + lane], h1 = h4[s1 * 64 + lane];
        float4 h2 = h4[s2 * 64 + lane], h3 = h4[s3 * 64 + lane];
        a0.x += w0 * h0.x; a0.y += w0 * h0.y; a0.z += w0 * h0.z; a0.w += w0 * h0.w;
        a1.x += w1 * h1.x; a1.y += w1 * h1.y; a1.z += w1 * h1.z; a1.w += w1 * h1.w;
        a2.x += w2 * h2.x; a2.y += w2 * h2.y; a2.z += w2 * h2.z; a2.w += w2 * h2.w;
        a3.x += w3 * h3.x; a3.y += w3 * h3.y; a3.z += w3 * h3.z; a3.w += w3 * h3.w;
    }
    for (; j < end; ++j) {
        int s = bsi[j];
        float w = bw[j * 4 + head];
        float4 hv = h4[s * 64 + lane];
        a0.x += w * hv.x; a0.y += w * hv.y; a0.z += w * hv.z; a0.w += w * hv.w;
    }
    float4 bb = ((const float4*)b)[lane];
    float4 o;
    o.x = a0.x + a1.x + a2.x + a3.x + bb.x;
    o.y = a0.y + a1.y + a2.y + a3.y + bb.y;
    o.z = a0.z + a1.z + a2.z + a3.z + bb.z;
    o.w = a0.w + a1.w + a2.w + a3.w + bb.w;
    ((float4*)out)[n * 64 + lane] = o;
}

extern "C" void kernel_launch(void* const* d_in, const int* in_sizes, int n_in,
                              void* d_out, int out_size, void* d_ws, size_t ws_size,
                              hipStream_t stream) {
    const float* x   = (const float*)d_in[0];
    const float* W   = (const float*)d_in[1];
    const float* att = (const float*)d_in[2];
    const float* b   = (const float*)d_in[3];
    const int*  eidx = (const int*)d_in[4];
    const int* es = eidx;        // edge_index[0] : sources
    const int* ed = eidx + EE;   // edge_index[1] : destinations
    float* out = (float*)d_out;

    float* ws = (float*)d_ws;
    float* h      = ws;                        // 5,120,000 f
    float* as     = h + NN * 256;              // 80,000 f (becomes Es in place)
    float* ad     = as + NN * 4;               // 80,000 f (becomes Ed in place)
    int*   cnt    = (int*)(ad + NN * 4);       // 20,000 i
    int*   offs   = cnt + NN;                  // 20,008 i (sentinel + pad)
    int*   cursor = offs + NN + 8;             // 20,000 i
    int*   bsi    = cursor + NN;               // 340,000 i
    float4* bw    = (float4*)(bsi + TE);       // 340,000 f4 (5.44 MB)
    float* bmaxT  = (float*)(bw + TE);         // 8 x 1280 f
    float4* psum  = (float4*)(bmaxT + 8 * 1280); // NB_SCORE f4
    float* hstat  = (float*)(psum + NB_SCORE + 3); // 4 f (invZ), 16B-aligned

    k_gemm  <<<NB_GEMM, 256, 0, stream>>>(x, W, att, h, as, ad, bmaxT, cnt);
    k_escale<<<(NN + 255) / 256, 256, 0, stream>>>(bmaxT, as, ad);
    k_score <<<NB_SCORE, 256, 0, stream>>>(es, ed, as, ad, psum, cnt);
    k_scanc <<<1, 1024, 0, stream>>>(cnt, offs, cursor, psum, hstat);
    k_fill  <<<NB_SCORE, 256, 0, stream>>>(es, ed, as, ad, hstat, cursor, bsi, bw);
    k_gather<<<NN / 4, 256, 0, stream>>>(offs, bsi, (const float*)bw, h, b, out);
}